// Round 1
// baseline (42.531 us; speedup 1.0000x reference)
//
#include <hip/hip_runtime.h>
#include <hip/hip_bf16.h>

// GPTQ W4A32 linear: x(16,4096) @ dequant(qweight(512,11008), scales(32,11008),
// qzeros(32,1376)) -> out(16,11008), fp32 throughout.
// W[k][n] = s[g][n] * w4[k][n] - s[g][n] * z4[g][n],  g = k/128
// w4 packed 8-per-int32 along k (shift 4*(k%8)); z4 packed 8-per-int32 along n
// (shift 4*(n%8)). Zeros are NOT incremented (reference uses raw extraction).

#define M_DIM 16
#define K_DIM 4096
#define N_DIM 11008
#define GS 128
#define KSPLIT 16
#define KC (K_DIM / KSPLIT)   // 256 k per chunk (2 groups)
#define NB 256                // n-columns per block (= threads per block)

__global__ __launch_bounds__(NB) void qlin_main(
    const float* __restrict__ x,
    const int*   __restrict__ qweight,
    const float* __restrict__ scales,
    const int*   __restrict__ qzeros,
    float*       __restrict__ outp,   // partials [chunk][M][N] or out [M][N]
    int nchunks)                      // chunks handled per block
{
    __shared__ float xs[KC * M_DIM];  // [k][m], 16 KiB

    const int n   = blockIdx.x * NB + threadIdx.x;
    const int kc0 = blockIdx.y * nchunks;

    float acc[M_DIM];
#pragma unroll
    for (int m = 0; m < M_DIM; ++m) acc[m] = 0.f;

    for (int c = 0; c < nchunks; ++c) {
        const int kbase = (kc0 + c) * KC;

        __syncthreads();  // protect xs before overwrite (no-op cost on first iter)
        // Stage x chunk: read coalesced (contiguous k within one m row),
        // write transposed [k][m].
        for (int i = threadIdx.x; i < KC * M_DIM; i += NB) {
            int m = i / KC;
            int k = i % KC;
            xs[k * M_DIM + m] = x[m * K_DIM + kbase + k];
        }
        __syncthreads();

#pragma unroll
        for (int gi = 0; gi < KC / GS; ++gi) {      // 2 groups per chunk
            const int g = kbase / GS + gi;
            const float s = scales[g * N_DIM + n];
            const unsigned zq = (unsigned)qzeros[g * (N_DIM / 8) + (n >> 3)];
            const float z = (float)((zq >> ((n & 7) * 4)) & 15u);
            const float nsz = -s * z;               // fold: t = s*w - s*z
            const int rbase = (kbase + gi * GS) >> 3;  // 16 qweight rows per group

            for (int r = 0; r < GS / 8; ++r) {
                const unsigned qw = (unsigned)qweight[(size_t)(rbase + r) * N_DIM + n];
                const int kl = gi * GS + r * 8;
#pragma unroll
                for (int j = 0; j < 8; ++j) {
                    const float w = (float)((qw >> (4 * j)) & 15u);
                    const float t = fmaf(s, w, nsz);
                    const float* xp = &xs[(kl + j) * M_DIM];
#pragma unroll
                    for (int m = 0; m < M_DIM; ++m)
                        acc[m] = fmaf(t, xp[m], acc[m]);
                }
            }
        }
    }

#pragma unroll
    for (int m = 0; m < M_DIM; ++m)
        outp[(size_t)(blockIdx.y * M_DIM + m) * N_DIM + n] = acc[m];
}

__global__ __launch_bounds__(256) void qlin_reduce(
    const float* __restrict__ part, float* __restrict__ out)
{
    const int i = blockIdx.x * 256 + threadIdx.x;  // over M*N
    if (i < M_DIM * N_DIM) {
        float s = 0.f;
#pragma unroll
        for (int c = 0; c < KSPLIT; ++c)
            s += part[(size_t)c * M_DIM * N_DIM + i];
        out[i] = s;
    }
}

extern "C" void kernel_launch(void* const* d_in, const int* in_sizes, int n_in,
                              void* d_out, int out_size, void* d_ws, size_t ws_size,
                              hipStream_t stream) {
    const float* x       = (const float*)d_in[0];
    const int*   qweight = (const int*)d_in[1];
    const float* scales  = (const float*)d_in[2];
    const int*   qzeros  = (const int*)d_in[3];
    float*       out     = (float*)d_out;

    const size_t need = (size_t)KSPLIT * M_DIM * N_DIM * sizeof(float);
    if (ws_size >= need) {
        dim3 grid(N_DIM / NB, KSPLIT);
        qlin_main<<<grid, NB, 0, stream>>>(x, qweight, scales, qzeros,
                                           (float*)d_ws, 1);
        qlin_reduce<<<(M_DIM * N_DIM + 255) / 256, 256, 0, stream>>>(
            (const float*)d_ws, out);
    } else {
        // Fallback: no workspace — each block walks all K chunks, writes out directly.
        dim3 grid(N_DIM / NB, 1);
        qlin_main<<<grid, NB, 0, stream>>>(x, qweight, scales, qzeros,
                                           out, KSPLIT);
    }
}

// Round 2
// 29.753 us; speedup vs baseline: 1.4295x; 1.4295x over previous
//
#include <hip/hip_runtime.h>
#include <hip/hip_bf16.h>

// GPTQ W4A32 linear via bf16 MFMA: out(16,11008) = x(16,4096) @ W
// W[k][n] = s[g][n]*w4[k][n] - s[g][n]*z4[g][n], g=k/128 (zeros NOT +1'd).
// qweight packs 8 consecutive k per dword (shift 4*(k%8)) -> exactly the
// mfma_f32_16x16x32_bf16 B-fragment (lane l: n=l&15, k=(l>>4)*8+j, j=0..7).
// A-fragment: lane l holds x[m=l&15][k=(l>>4)*8+j] (bf16, pre-cast kernel).
// C/D: lane l, reg r -> row m=(l>>4)*4+r, col n=l&15  [m89-verified mapping].

#define M_DIM 16
#define K_DIM 4096
#define N_DIM 11008
#define GS 128
#define KSPLIT 8
#define KC (K_DIM / KSPLIT)      // 512 k per chunk = 16 mfma steps
#define WPB 4                    // waves per block (256 threads)

typedef __attribute__((ext_vector_type(8))) short short8;
typedef __attribute__((ext_vector_type(4))) float f32x4;

// x f32 -> bf16 (RNE), row-major [m][k]
__global__ __launch_bounds__(256) void qlin_xcast(const float* __restrict__ x,
                                                  unsigned short* __restrict__ xb) {
    int i = blockIdx.x * 256 + threadIdx.x;
    if (i < M_DIM * K_DIM) {
        union { float f; unsigned u; } c; c.f = x[i];
        unsigned u = c.u;
        xb[i] = (unsigned short)((u + 0x7FFFu + ((u >> 16) & 1u)) >> 16);
    }
}

__global__ __launch_bounds__(256) void qlin_mfma(
    const int*   __restrict__ qweight,
    const float* __restrict__ scales,
    const int*   __restrict__ qzeros,
    const unsigned short* __restrict__ xb,
    float*       __restrict__ outp,     // partials [chunkset][16][N] or out
    int nchunks)
{
    const int lane = threadIdx.x & 63;
    const int wave = threadIdx.x >> 6;
    const int lmod = lane & 15;          // n-col / m-row selector
    const int lhi  = lane >> 4;          // 0..3
    const int n    = (blockIdx.x * WPB + wave) * 16 + lmod;
    const int kbase0 = blockIdx.y * nchunks * KC;

    f32x4 acc = {0.f, 0.f, 0.f, 0.f};

    for (int c = 0; c < nchunks; ++c) {
        const int kbase = kbase0 + c * KC;
#pragma unroll
        for (int g4 = 0; g4 < KC / GS; ++g4) {       // 4 groups per chunk
            const int g = (kbase + g4 * GS) / GS;
            const float s = scales[g * N_DIM + n];
            const unsigned zq = (unsigned)qzeros[g * (N_DIM / 8) + (n >> 3)];
            const float z = (float)((zq >> ((n & 7) * 4)) & 15u);
            const float nsz = -s * z;                 // t = s*w + nsz
#pragma unroll
            for (int t = 0; t < GS / 32; ++t) {       // 4 mfma per group
                const int k = kbase + g4 * GS + t * 32;
                const unsigned qw =
                    (unsigned)qweight[(size_t)((k >> 3) + lhi) * N_DIM + n];
                union { short8 v; unsigned u[4]; } b;
#pragma unroll
                for (int p = 0; p < 4; ++p) {
                    const float w0 = (float)((qw >> (8 * p)) & 15u);
                    const float w1 = (float)((qw >> (8 * p + 4)) & 15u);
                    const float t0 = fmaf(s, w0, nsz);
                    const float t1 = fmaf(s, w1, nsz);
                    unsigned pk;
                    asm("v_cvt_pk_bf16_f32 %0, %1, %2"
                        : "=v"(pk) : "v"(t0), "v"(t1));
                    b.u[p] = pk;
                }
                const short8 a =
                    *(const short8*)(xb + (size_t)lmod * K_DIM + k + lhi * 8);
                acc = __builtin_amdgcn_mfma_f32_16x16x32_bf16(a, b.v, acc, 0, 0, 0);
            }
        }
    }

#pragma unroll
    for (int r = 0; r < 4; ++r) {
        const int m = lhi * 4 + r;
        outp[(size_t)(blockIdx.y * M_DIM + m) * N_DIM + n] = acc[r];
    }
}

__global__ __launch_bounds__(256) void qlin_reduce(
    const float* __restrict__ part, float* __restrict__ out)
{
    const int i = blockIdx.x * 256 + threadIdx.x;   // over M*N
    if (i < M_DIM * N_DIM) {
        float sum = 0.f;
#pragma unroll
        for (int c = 0; c < KSPLIT; ++c)
            sum += part[(size_t)c * M_DIM * N_DIM + i];
        out[i] = sum;
    }
}

extern "C" void kernel_launch(void* const* d_in, const int* in_sizes, int n_in,
                              void* d_out, int out_size, void* d_ws, size_t ws_size,
                              hipStream_t stream) {
    const float* x       = (const float*)d_in[0];
    const int*   qweight = (const int*)d_in[1];
    const float* scales  = (const float*)d_in[2];
    const int*   qzeros  = (const int*)d_in[3];
    float*       out     = (float*)d_out;

    const size_t xb_bytes   = (size_t)M_DIM * K_DIM * sizeof(unsigned short); // 128 KB
    const size_t part_bytes = (size_t)KSPLIT * M_DIM * N_DIM * sizeof(float); // 5.6 MB
    unsigned short* xb   = (unsigned short*)d_ws;
    float*          part = (float*)((char*)d_ws + ((xb_bytes + 255) & ~(size_t)255));

    qlin_xcast<<<(M_DIM * K_DIM + 255) / 256, 256, 0, stream>>>(x, xb);

    if (ws_size >= xb_bytes + 256 + part_bytes) {
        dim3 grid(N_DIM / 16 / WPB, KSPLIT);        // (172, 8)
        qlin_mfma<<<grid, 256, 0, stream>>>(qweight, scales, qzeros, xb, part, 1);
        qlin_reduce<<<(M_DIM * N_DIM + 255) / 256, 256, 0, stream>>>(part, out);
    } else {
        // minimal-workspace fallback: one K-sweep per wave, write out directly
        dim3 grid(N_DIM / 16 / WPB, 1);
        qlin_mfma<<<grid, 256, 0, stream>>>(qweight, scales, qzeros, xb, out, KSPLIT);
    }
}

// Round 3
// 25.382 us; speedup vs baseline: 1.6756x; 1.1722x over previous
//
#include <hip/hip_runtime.h>

// GPTQ W4A32 linear via bf16 MFMA with magic-mantissa dequant.
// out(16,11008) = x(16,4096) @ W,  W[k][n] = s[g][n]*(w4[k][n] - z4[g][n]).
// Trick: bf16 bits (0x4380 | w) == 256 + 2w exactly. MFMA on those raw values
// gives P_raw = 256*X + 2*P per group, where X = sum of (bf16-rounded) x over
// the group. Per-group epilogue: out += (s/2)*P_raw - s*(128+z)*X.
// B-frag nibble order from the mask trick is k = {0,4,1,5,2,6,3,7} per 8;
// xb is pre-permuted identically so A loads stay contiguous short8.

#define M_DIM 16
#define K_DIM 4096
#define N_DIM 11008
#define GS 128
#define NG (K_DIM / GS)          // 32 groups
#define WPB 4                    // waves per block; waves split K
#define KW (K_DIM / WPB)         // 1024 k per wave -> 8 groups per wave

typedef __attribute__((ext_vector_type(8))) short short8;
typedef __attribute__((ext_vector_type(4))) float f32x4;

__device__ __forceinline__ float bf16lo_to_f32(unsigned w) {
    union { unsigned u; float f; } c; c.u = w << 16; return c.f;
}
__device__ __forceinline__ float bf16hi_to_f32(unsigned w) {
    union { unsigned u; float f; } c; c.u = w & 0xFFFF0000u; return c.f;
}

// Per group g: cast x to bf16 (RNE via v_cvt_pk), store k-permuted
// {0,4,1,5,2,6,3,7}, and compute X[g][m] = sum of rounded values (f32).
__global__ __launch_bounds__(256) void qlin_prep(
    const float* __restrict__ x,
    unsigned short* __restrict__ xb,   // [m][k] bf16, permuted within each 8
    float* __restrict__ Xtab)          // [g][m]
{
    __shared__ float psum[256];
    const int g  = blockIdx.x;
    const int t  = threadIdx.x;
    const int m  = t >> 4;             // 0..15
    const int k8 = t & 15;             // which 8-block within group
    const int kbase = g * GS + k8 * 8;

    const float* xp = x + (size_t)m * K_DIM + kbase;
    float v[8];
#pragma unroll
    for (int j = 0; j < 8; ++j) v[j] = xp[j];

    union { short8 s; unsigned u[4]; } pk;
    asm("v_cvt_pk_bf16_f32 %0, %1, %2" : "=v"(pk.u[0]) : "v"(v[0]), "v"(v[4]));
    asm("v_cvt_pk_bf16_f32 %0, %1, %2" : "=v"(pk.u[1]) : "v"(v[1]), "v"(v[5]));
    asm("v_cvt_pk_bf16_f32 %0, %1, %2" : "=v"(pk.u[2]) : "v"(v[2]), "v"(v[6]));
    asm("v_cvt_pk_bf16_f32 %0, %1, %2" : "=v"(pk.u[3]) : "v"(v[3]), "v"(v[7]));
    *(short8*)(xb + (size_t)m * K_DIM + kbase) = pk.s;

    float s = 0.f;
#pragma unroll
    for (int p = 0; p < 4; ++p)
        s += bf16lo_to_f32(pk.u[p]) + bf16hi_to_f32(pk.u[p]);
    psum[t] = s;
    __syncthreads();
    if (t < 16) {
        float X = 0.f;
#pragma unroll
        for (int i = 0; i < 16; ++i) X += psum[t * 16 + i];
        Xtab[g * 16 + t] = X;
    }
}

__global__ __launch_bounds__(256) void qlin_mfma(
    const int*   __restrict__ qweight,
    const float* __restrict__ scales,
    const int*   __restrict__ qzeros,
    const unsigned short* __restrict__ xb,
    const float* __restrict__ Xtab,
    float*       __restrict__ out)
{
    __shared__ float Xl[NG * 16];      // 2 KiB
    __shared__ f32x4 red[WPB * 64];    // 4 KiB

    const int tid  = threadIdx.x;
    const int lane = tid & 63, wave = tid >> 6;
    const int lmod = lane & 15, lhi = lane >> 4;
    const int n    = blockIdx.x * 16 + lmod;

    for (int i = tid; i < NG * 16; i += 256) Xl[i] = Xtab[i];
    __syncthreads();

    f32x4 outacc = {0.f, 0.f, 0.f, 0.f};
    const int g0 = wave * (KW / GS);

#pragma unroll 2
    for (int gi = 0; gi < KW / GS; ++gi) {
        const int g = g0 + gi;
        const float s = scales[g * N_DIM + n];
        const unsigned zq = (unsigned)qzeros[g * (N_DIM / 8) + (n >> 3)];
        const float z = (float)((zq >> ((n & 7) * 4)) & 15u);

        f32x4 acc = {0.f, 0.f, 0.f, 0.f};
#pragma unroll
        for (int t = 0; t < 4; ++t) {
            const int k = g * GS + t * 32;
            const unsigned qw =
                (unsigned)qweight[(size_t)((k >> 3) + lhi) * N_DIM + n];
            union { short8 v; unsigned u[4]; } b;
            b.u[0] = ( qw        & 0x000F000Fu) | 0x43804380u;
            b.u[1] = ((qw >> 4)  & 0x000F000Fu) | 0x43804380u;
            b.u[2] = ((qw >> 8)  & 0x000F000Fu) | 0x43804380u;
            b.u[3] = ((qw >> 12) & 0x000F000Fu) | 0x43804380u;
            const short8 a =
                *(const short8*)(xb + (size_t)lmod * K_DIM + k + lhi * 8);
            acc = __builtin_amdgcn_mfma_f32_16x16x32_bf16(a, b.v, acc, 0, 0, 0);
        }
        const f32x4 x4 = *(const f32x4*)&Xl[g * 16 + lhi * 4];
        const float s2 = 0.5f * s;
        const float c  = -s * (128.0f + z);
#pragma unroll
        for (int r = 0; r < 4; ++r)
            outacc[r] = fmaf(s2, acc[r], fmaf(c, x4[r], outacc[r]));
    }

    red[wave * 64 + lane] = outacc;
    __syncthreads();
    if (wave == 0) {
        const f32x4 r0 = red[lane];
        const f32x4 r1 = red[64 + lane];
        const f32x4 r2 = red[128 + lane];
        const f32x4 r3 = red[192 + lane];
#pragma unroll
        for (int r = 0; r < 4; ++r)
            out[(size_t)(lhi * 4 + r) * N_DIM + n] =
                (r0[r] + r1[r]) + (r2[r] + r3[r]);
    }
}

extern "C" void kernel_launch(void* const* d_in, const int* in_sizes, int n_in,
                              void* d_out, int out_size, void* d_ws, size_t ws_size,
                              hipStream_t stream) {
    const float* x       = (const float*)d_in[0];
    const int*   qweight = (const int*)d_in[1];
    const float* scales  = (const float*)d_in[2];
    const int*   qzeros  = (const int*)d_in[3];
    float*       out     = (float*)d_out;

    unsigned short* xb   = (unsigned short*)d_ws;                   // 128 KiB
    float*          Xtab = (float*)((char*)d_ws + 131072);          // 2 KiB

    qlin_prep<<<NG, 256, 0, stream>>>(x, xb, Xtab);
    qlin_mfma<<<N_DIM / 16, 256, 0, stream>>>(qweight, scales, qzeros,
                                              xb, Xtab, out);
}

// Round 4
// 16.027 us; speedup vs baseline: 2.6538x; 1.5837x over previous
//
#include <hip/hip_runtime.h>

// GPTQ W4A32 linear via bf16 MFMA, magic-mantissa dequant, fused x-staging.
// out(16,11008) = x(16,4096) @ W,  W[k][n] = s[g][n]*(w4[k][n] - z4[g][n]).
// bf16 bits (0x4380|w) == 256+2w exactly -> MFMA on raw nibbles gives
// P_raw = 256*X + 2*P per group (X = group-sum of bf16-rounded x), fixed up as
// out += (s/2)*P_raw - s*(128+z)*X.  Nibble order from the mask trick is
// k={0,4,1,5,2,6,3,7} per 8; x is staged into LDS with the same permutation.
// LDS is XOR-swizzled (byte ^= (m&7)<<4) so A-frag ds_read_b128 hits the
// 8-cycle minimum instead of 16.

#define M_DIM 16
#define K_DIM 4096
#define N_DIM 11008
#define GS 128
#define KSPLIT 8
#define KC (K_DIM / KSPLIT)      // 512 k per block
#define GPC (KC / GS)            // 4 groups per chunk
#define BLOCKN 64                // 4 waves x 16 n, each wave owns its strip

typedef __attribute__((ext_vector_type(8))) short short8;
typedef __attribute__((ext_vector_type(4))) float f32x4;

__device__ __forceinline__ float bfl(unsigned w) {
    union { unsigned u; float f; } c; c.u = w << 16; return c.f;
}
__device__ __forceinline__ float bfh(unsigned w) {
    union { unsigned u; float f; } c; c.u = w & 0xFFFF0000u; return c.f;
}

__global__ __launch_bounds__(256) void qlin_fused(
    const float* __restrict__ x,
    const int*   __restrict__ qweight,
    const float* __restrict__ scales,
    const int*   __restrict__ qzeros,
    float*       __restrict__ outp,   // partials [ksplit][16][N] or out [16][N]
    int nchunks)
{
    __shared__ __align__(16) unsigned short xs[M_DIM * KC];  // 16 KiB, swizzled
    __shared__ __align__(16) float Xl[GPC * 16];

    const int tid  = threadIdx.x;
    const int lane = tid & 63, wave = tid >> 6;
    const int lmod = lane & 15, lhi = lane >> 4;
    const int n    = blockIdx.x * BLOCKN + wave * 16 + lmod;
    const int swzA = (lmod & 7) << 4;

    f32x4 outacc = {0.f, 0.f, 0.f, 0.f};

    for (int c = 0; c < nchunks; ++c) {
        const int ky0 = (blockIdx.y * nchunks + c) * KC;

        __syncthreads();   // protect xs/Xl before overwrite
        // ---- stage x[16][KC]: f32 -> bf16 (RNE), nibble-permuted, swizzled
#pragma unroll
        for (int i = 0; i < (M_DIM * KC / 8) / 256; ++i) {   // 4 iters
            const int idx = i * 256 + tid;
            const int m  = idx >> 6;          // KC/8 == 64 chunks per row
            const int cc = idx & 63;
            const float4* xp =
                (const float4*)(x + (size_t)m * K_DIM + ky0 + cc * 8);
            const float4 v0 = xp[0], v1 = xp[1];
            union { short8 s; unsigned u[4]; } pk;
            asm("v_cvt_pk_bf16_f32 %0, %1, %2" : "=v"(pk.u[0]) : "v"(v0.x), "v"(v1.x));
            asm("v_cvt_pk_bf16_f32 %0, %1, %2" : "=v"(pk.u[1]) : "v"(v0.y), "v"(v1.y));
            asm("v_cvt_pk_bf16_f32 %0, %1, %2" : "=v"(pk.u[2]) : "v"(v0.z), "v"(v1.z));
            asm("v_cvt_pk_bf16_f32 %0, %1, %2" : "=v"(pk.u[3]) : "v"(v0.w), "v"(v1.w));
            const int byte = ((m * KC + cc * 8) * 2) ^ ((m & 7) << 4);
            *(short8*)((char*)xs + byte) = pk.s;
        }
        __syncthreads();

        // ---- X[g][m] = group-sum of staged bf16 (wave w handles group w)
        {
            const int g = wave;
            float xv = 0.f;
#pragma unroll
            for (int q = 0; q < 4; ++q) {
                const int byte =
                    ((lmod * KC + g * GS + lhi * 32 + q * 8) * 2) ^ swzA;
                union { short8 s; unsigned u[4]; } a;
                a.s = *(const short8*)((const char*)xs + byte);
#pragma unroll
                for (int p = 0; p < 4; ++p) xv += bfl(a.u[p]) + bfh(a.u[p]);
            }
            xv += __shfl_xor(xv, 16, 64);
            xv += __shfl_xor(xv, 32, 64);
            if (lane < 16) Xl[g * 16 + lane] = xv;
        }
        __syncthreads();

        // ---- MFMA over 4 groups
        const int rowbase = ky0 >> 3;
#pragma unroll
        for (int g = 0; g < GPC; ++g) {
            const int G = ky0 / GS + g;
            const float s = scales[G * N_DIM + n];
            const unsigned zq = (unsigned)qzeros[G * (N_DIM / 8) + (n >> 3)];
            const float z = (float)((zq >> ((n & 7) * 4)) & 15u);

            f32x4 acc = {0.f, 0.f, 0.f, 0.f};
#pragma unroll
            for (int t = 0; t < 4; ++t) {
                const unsigned qw = (unsigned)
                    qweight[(size_t)(rowbase + g * 16 + t * 4 + lhi) * N_DIM + n];
                union { short8 v; unsigned u[4]; } b;
                b.u[0] = ( qw        & 0x000F000Fu) | 0x43804380u;
                b.u[1] = ((qw >> 4)  & 0x000F000Fu) | 0x43804380u;
                b.u[2] = ((qw >> 8)  & 0x000F000Fu) | 0x43804380u;
                b.u[3] = ((qw >> 12) & 0x000F000Fu) | 0x43804380u;
                const int byte =
                    ((lmod * KC + g * GS + t * 32 + lhi * 8) * 2) ^ swzA;
                const short8 a = *(const short8*)((const char*)xs + byte);
                acc = __builtin_amdgcn_mfma_f32_16x16x32_bf16(a, b.v, acc, 0, 0, 0);
            }
            const f32x4 x4 = *(const f32x4*)&Xl[g * 16 + lhi * 4];
            const float s2 = 0.5f * s;
            const float zc = -s * (128.0f + z);
#pragma unroll
            for (int r = 0; r < 4; ++r)
                outacc[r] = fmaf(s2, acc[r], fmaf(zc, x4[r], outacc[r]));
        }
    }

#pragma unroll
    for (int r = 0; r < 4; ++r)
        outp[(size_t)(blockIdx.y * M_DIM + lhi * 4 + r) * N_DIM + n] = outacc[r];
}

__global__ __launch_bounds__(256) void qlin_reduce(
    const float* __restrict__ part, float* __restrict__ out)
{
    const int i = blockIdx.x * 256 + threadIdx.x;   // over M*N
    if (i < M_DIM * N_DIM) {
        float s = 0.f;
#pragma unroll
        for (int c = 0; c < KSPLIT; ++c)
            s += part[(size_t)c * M_DIM * N_DIM + i];
        out[i] = s;
    }
}

extern "C" void kernel_launch(void* const* d_in, const int* in_sizes, int n_in,
                              void* d_out, int out_size, void* d_ws, size_t ws_size,
                              hipStream_t stream) {
    const float* x       = (const float*)d_in[0];
    const int*   qweight = (const int*)d_in[1];
    const float* scales  = (const float*)d_in[2];
    const int*   qzeros  = (const int*)d_in[3];
    float*       out     = (float*)d_out;

    const size_t part_bytes = (size_t)KSPLIT * M_DIM * N_DIM * sizeof(float);
    if (ws_size >= part_bytes) {
        float* part = (float*)d_ws;
        dim3 grid(N_DIM / BLOCKN, KSPLIT);          // (172, 8)
        qlin_fused<<<grid, 256, 0, stream>>>(x, qweight, scales, qzeros, part, 1);
        qlin_reduce<<<(M_DIM * N_DIM + 255) / 256, 256, 0, stream>>>(part, out);
    } else {
        dim3 grid(N_DIM / BLOCKN, 1);
        qlin_fused<<<grid, 256, 0, stream>>>(x, qweight, scales, qzeros, out,
                                             KSPLIT);
    }
}